// Round 5
// baseline (86.725 us; speedup 1.0000x reference)
//
#include <hip/hip_runtime.h>

// FeedForwardQuantum: out = relu(cos(x+theta) @ W1 + b1) @ W2 + b2
// x: [B,S,E=8] fp32, W1: [8,32], W2: [32,8]. 524288 tokens of 8 floats.
//
// R5: two-kernel scheme.
//  prep_kernel (1 block, 32 thr): packs per-f weight records into d_ws:
//    rec[f] = { W1col_f[8], W2row_f[8], b1[f] }  stride 32 floats (128 B).
//  ffq_kernel: per f-iter reads ONE contiguous 80 B record via uniform
//    address -> 2 scalar loads (s_load_dwordx16 + x4), SW-pipelined at
//    distance 1 so the ~200cyc K$ latency hides under the 136-cyc FMA
//    block. No LDS, no barrier, no strided scalar-load storm (R4's bug:
//    8 scattered s_loads/iter + lgkmcnt(0) drains -> ~18us).
//  TOKT=2 -> 4096 waves (16 waves/CU), VGPR ~64 -> deep latency hiding.

#define TPB 256
#define TOKT 2
#define RECS 32          // floats per weight record (padded)

__global__ void prep_kernel(const float* __restrict__ w1,
                            const float* __restrict__ b1,
                            const float* __restrict__ w2,
                            float* __restrict__ wrec) {
    int f = threadIdx.x;             // 32 threads, one per f
    float* r = wrec + f * RECS;
#pragma unroll
    for (int e = 0; e < 8; ++e) r[e]     = w1[e * 32 + f];   // W1 column f
#pragma unroll
    for (int e = 0; e < 8; ++e) r[8 + e] = w2[f * 8 + e];    // W2 row f
    r[16] = b1[f];
}

__global__ __launch_bounds__(TPB) void ffq_kernel(
    const float4* __restrict__ xv,      // x as float4 pairs: token g -> xv[2g], xv[2g+1]
    const float*  __restrict__ theta,   // [8]
    const float*  __restrict__ b2,      // [8]
    const float*  __restrict__ wrec,    // packed weight records in d_ws
    float4*       __restrict__ outv,
    int ntok)
{
    const int base   = blockIdx.x * TPB + threadIdx.x;
    const int stride = gridDim.x * TPB;

    // theta/b2: 16 uniform scalar loads, once.
    float th[8], bb2[8];
#pragma unroll
    for (int e = 0; e < 8; ++e) { th[e] = theta[e]; bb2[e] = b2[e]; }

    float4 a[TOKT], c[TOKT];
#pragma unroll
    for (int t = 0; t < TOKT; ++t) {
        int g = base + t * stride;
        if (g < ntok) {
            a[t] = xv[2 * g];
            c[t] = xv[2 * g + 1];
        } else {
            a[t] = make_float4(0.f, 0.f, 0.f, 0.f);
            c[t] = make_float4(0.f, 0.f, 0.f, 0.f);
        }
    }

    float q[TOKT][8];
    float o[TOKT][8];
#pragma unroll
    for (int t = 0; t < TOKT; ++t) {
        q[t][0] = __cosf(a[t].x + th[0]);
        q[t][1] = __cosf(a[t].y + th[1]);
        q[t][2] = __cosf(a[t].z + th[2]);
        q[t][3] = __cosf(a[t].w + th[3]);
        q[t][4] = __cosf(c[t].x + th[4]);
        q[t][5] = __cosf(c[t].y + th[5]);
        q[t][6] = __cosf(c[t].z + th[6]);
        q[t][7] = __cosf(c[t].w + th[7]);
#pragma unroll
        for (int e = 0; e < 8; ++e) o[t][e] = bb2[e];
    }

    // Preload record 0.
    float cwa[8], cva[8], cb1;
#pragma unroll
    for (int i = 0; i < 8; ++i) { cwa[i] = wrec[i]; cva[i] = wrec[8 + i]; }
    cb1 = wrec[16];

    // Rolled f-loop (unroll 2 only), distance-1 scalar prefetch:
    // per iter: issue next-record loads, 136-cyc FMA block on current,
    // then the lgkmcnt drain lands mostly covered.
#pragma unroll 2
    for (int f = 0; f < 32; ++f) {
        float nwa[8], nva[8], nb1;
        if (f < 31) {
            const float* nr = wrec + (f + 1) * RECS;
#pragma unroll
            for (int i = 0; i < 8; ++i) { nwa[i] = nr[i]; nva[i] = nr[8 + i]; }
            nb1 = nr[16];
        } else {
#pragma unroll
            for (int i = 0; i < 8; ++i) { nwa[i] = 0.f; nva[i] = 0.f; }
            nb1 = 0.f;
        }
#pragma unroll
        for (int t = 0; t < TOKT; ++t) {
            float h = cb1;
#pragma unroll
            for (int e = 0; e < 8; ++e) h = fmaf(q[t][e], cwa[e], h);
            h = fmaxf(h, 0.0f);
#pragma unroll
            for (int e = 0; e < 8; ++e) o[t][e] = fmaf(h, cva[e], o[t][e]);
        }
#pragma unroll
        for (int i = 0; i < 8; ++i) { cwa[i] = nwa[i]; cva[i] = nva[i]; }
        cb1 = nb1;
    }

#pragma unroll
    for (int t = 0; t < TOKT; ++t) {
        int g = base + t * stride;
        if (g < ntok) {
            outv[2 * g]     = make_float4(o[t][0], o[t][1], o[t][2], o[t][3]);
            outv[2 * g + 1] = make_float4(o[t][4], o[t][5], o[t][6], o[t][7]);
        }
    }
}

extern "C" void kernel_launch(void* const* d_in, const int* in_sizes, int n_in,
                              void* d_out, int out_size, void* d_ws, size_t ws_size,
                              hipStream_t stream) {
    const float* x     = (const float*)d_in[0];
    const float* theta = (const float*)d_in[1];
    const float* w1    = (const float*)d_in[2];
    const float* b1    = (const float*)d_in[3];
    const float* w2    = (const float*)d_in[4];
    const float* b2    = (const float*)d_in[5];
    float* out  = (float*)d_out;
    float* wrec = (float*)d_ws;   // 32 records x 32 floats = 4 KB

    const int ntok = in_sizes[0] / 8;  // B*S tokens
    const int total_threads = (ntok + TOKT - 1) / TOKT;
    const int grid = (total_threads + TPB - 1) / TPB;

    prep_kernel<<<1, 32, 0, stream>>>(w1, b1, w2, wrec);
    ffq_kernel<<<grid, TPB, 0, stream>>>(
        (const float4*)x, theta, b2, wrec, (float4*)out, ntok);
}

// Round 6
// 83.694 us; speedup vs baseline: 1.0362x; 1.0362x over previous
//
#include <hip/hip_runtime.h>

// FeedForwardQuantum: out = relu(cos(x+theta) @ W1 + b1) @ W2 + b2
// x: [B,S,E=8] fp32, W1: [8,32], W2: [32,8]. 524288 tokens of 8 floats.
//
// R6: single dispatch (R5's prep kernel cost +2.7us of pure graph-replay
// dispatch overhead). Scalar-weight rolled f-loop (R4) but:
//  - TOKT=1 -> 2048 blocks = 8192 waves = 8 waves/SIMD (R4 was grid-capped
//    at 4): double the latency hiding for per-iter scalar drains + x load.
//  - 524288 tokens == 2048*256 exactly -> no bounds checks anywhere.
// Per-wave issue ~1300 cyc -> ~4.3us VALU floor, ~5us memory floor.
// R1(LDS)/R4(scalar) both hit bench=84.0 -> if this stays 84.0 the kernel
// is below the harness critical path and we're done.

#define TPB 256

__global__ __launch_bounds__(TPB, 8) void ffq_kernel(
    const float4* __restrict__ xv,      // x as float4 pairs: token g -> xv[2g], xv[2g+1]
    const float*  __restrict__ theta,   // [8]
    const float*  __restrict__ w1,      // [8][32] row-major
    const float*  __restrict__ b1,      // [32]
    const float*  __restrict__ w2,      // [32][8] row-major
    const float*  __restrict__ b2,      // [8]
    float4*       __restrict__ outv)    // out as float4 pairs
{
    const int g = blockIdx.x * TPB + threadIdx.x;   // token id, exact fit

    // theta/b2: 16 uniform scalar loads, hoisted once.
    float th[8], bb2[8];
#pragma unroll
    for (int e = 0; e < 8; ++e) { th[e] = theta[e]; bb2[e] = b2[e]; }

    const float4 a = xv[2 * g];
    const float4 c = xv[2 * g + 1];

    float q[8], o[8];
    q[0] = __cosf(a.x + th[0]);
    q[1] = __cosf(a.y + th[1]);
    q[2] = __cosf(a.z + th[2]);
    q[3] = __cosf(a.w + th[3]);
    q[4] = __cosf(c.x + th[4]);
    q[5] = __cosf(c.y + th[5]);
    q[6] = __cosf(c.z + th[6]);
    q[7] = __cosf(c.w + th[7]);
#pragma unroll
    for (int e = 0; e < 8; ++e) o[e] = bb2[e];

    // Rolled f-loop (unroll 2): ~20 live SGPRs of weights per iter,
    // uniform addresses -> s_load; v_fmac consumes SGPR operands directly.
#pragma unroll 2
    for (int f = 0; f < 32; ++f) {
        const float bb = b1[f];
        float wa[8], wb[8];
#pragma unroll
        for (int e = 0; e < 8; ++e) wa[e] = w1[e * 32 + f];   // W1 column f (uniform)
#pragma unroll
        for (int e = 0; e < 8; ++e) wb[e] = w2[f * 8 + e];    // W2 row f (uniform)
        float h = bb;
#pragma unroll
        for (int e = 0; e < 8; ++e) h = fmaf(q[e], wa[e], h);
        h = fmaxf(h, 0.0f);
#pragma unroll
        for (int e = 0; e < 8; ++e) o[e] = fmaf(h, wb[e], o[e]);
    }

    outv[2 * g]     = make_float4(o[0], o[1], o[2], o[3]);
    outv[2 * g + 1] = make_float4(o[4], o[5], o[6], o[7]);
}

extern "C" void kernel_launch(void* const* d_in, const int* in_sizes, int n_in,
                              void* d_out, int out_size, void* d_ws, size_t ws_size,
                              hipStream_t stream) {
    const float* x     = (const float*)d_in[0];
    const float* theta = (const float*)d_in[1];
    const float* w1    = (const float*)d_in[2];
    const float* b1    = (const float*)d_in[3];
    const float* w2    = (const float*)d_in[4];
    const float* b2    = (const float*)d_in[5];
    float* out = (float*)d_out;

    const int ntok = in_sizes[0] / 8;          // 524288 tokens
    const int grid = (ntok + TPB - 1) / TPB;   // 2048 blocks, exact fit

    ffq_kernel<<<grid, TPB, 0, stream>>>(
        (const float4*)x, theta, w1, b1, w2, b2, (float4*)out);
}

// Round 7
// 83.270 us; speedup vs baseline: 1.0415x; 1.0051x over previous
//
#include <hip/hip_runtime.h>

// FeedForwardQuantum: out = relu(cos(x+theta) @ W1 + b1) @ W2 + b2
// x: [B,S,E=8] fp32, W1: [8,32], W2: [32,8]. 524288 tokens of 8 floats.
//
// R7: LDS-broadcast weights + TOKT=2 + distance-1 prefetch.
//  - R4/R6 (~18us inferred) are scalar-pipe bound: ~320 s_loads/wave x
//    32 waves/CU on the shared per-CU scalar unit + K$ contention; more
//    waves/SIMD didn't help (shared-pipe, not latency).
//  - Weights move to LDS: wave64 same-address ds_read_b128 is a broadcast
//    (~4cyc, no conflict) -> LDS pipe ~3.4us at 16 waves/CU, overlapped.
//  - b1 stays on the scalar pipe (1 uniform s_load/iter) to split load.
//  - TOKT=2 -> grid 1024 -> 4 waves/SIMD (R1 was capped at 2), explicit
//    next-record prefetch hides the ~120cyc LDS latency under 136 FMA cyc.

#define TPB 256
#define TOKT 2

__global__ __launch_bounds__(TPB, 4) void ffq_kernel(
    const float4* __restrict__ xv,      // x as float4 pairs: token g -> xv[2g], xv[2g+1]
    const float*  __restrict__ theta,   // [8]
    const float*  __restrict__ w1,      // [8][32] row-major
    const float*  __restrict__ b1,      // [32]
    const float*  __restrict__ w2,      // [32][8] row-major
    const float*  __restrict__ b2,      // [8]
    float4*       __restrict__ outv)    // out as float4 pairs
{
    // wc[f][0..7] = W1[0..7][f] (W1 column f),  wc[f][8..15] = W2[f][0..7]
    __shared__ float wc[32 * 16];

    const int tid = threadIdx.x;
    {
        int e = tid >> 5, f = tid & 31;          // w1: tid = e*32+f
        wc[f * 16 + e] = w1[tid];
        int f2 = tid >> 3, e2 = tid & 7;         // w2: tid = f*8+e
        wc[f2 * 16 + 8 + e2] = w2[tid];
    }

    // theta/b2: 16 uniform scalar loads, hoisted once.
    float th[8], bb2[8];
#pragma unroll
    for (int e = 0; e < 8; ++e) { th[e] = theta[e]; bb2[e] = b2[e]; }

    const int base   = blockIdx.x * TPB + tid;       // exact fit: no guards
    const int stride = gridDim.x * TPB;              // 262144

    // Issue x loads before the barrier (HBM latency overlaps staging).
    float4 a[TOKT], c[TOKT];
#pragma unroll
    for (int t = 0; t < TOKT; ++t) {
        int g = base + t * stride;
        a[t] = xv[2 * g];
        c[t] = xv[2 * g + 1];
    }

    __syncthreads();

    float q[TOKT][8];
    float o[TOKT][8];
#pragma unroll
    for (int t = 0; t < TOKT; ++t) {
        q[t][0] = __cosf(a[t].x + th[0]);
        q[t][1] = __cosf(a[t].y + th[1]);
        q[t][2] = __cosf(a[t].z + th[2]);
        q[t][3] = __cosf(a[t].w + th[3]);
        q[t][4] = __cosf(c[t].x + th[4]);
        q[t][5] = __cosf(c[t].y + th[5]);
        q[t][6] = __cosf(c[t].z + th[6]);
        q[t][7] = __cosf(c[t].w + th[7]);
#pragma unroll
        for (int e = 0; e < 8; ++e) o[t][e] = bb2[e];
    }

    // f-loop: broadcast LDS reads, distance-1 prefetch, b1 on scalar pipe.
    const float4* wcv = (const float4*)wc;   // record f = wcv[4f .. 4f+3]
    float4 wa = wcv[0], wb = wcv[1], va = wcv[2], vb = wcv[3];
    float  bb = b1[0];

#pragma unroll 2
    for (int f = 0; f < 32; ++f) {
        float4 nwa, nwb, nva, nvb;
        float  nbb;
        if (f < 31) {
            nwa = wcv[4 * f + 4];
            nwb = wcv[4 * f + 5];
            nva = wcv[4 * f + 6];
            nvb = wcv[4 * f + 7];
            nbb = b1[f + 1];                 // uniform s_load, scalar pipe
        } else {
            nwa = nwb = nva = nvb = make_float4(0.f, 0.f, 0.f, 0.f);
            nbb = 0.f;
        }
#pragma unroll
        for (int t = 0; t < TOKT; ++t) {
            float h = bb;
            h = fmaf(q[t][0], wa.x, h);
            h = fmaf(q[t][1], wa.y, h);
            h = fmaf(q[t][2], wa.z, h);
            h = fmaf(q[t][3], wa.w, h);
            h = fmaf(q[t][4], wb.x, h);
            h = fmaf(q[t][5], wb.y, h);
            h = fmaf(q[t][6], wb.z, h);
            h = fmaf(q[t][7], wb.w, h);
            h = fmaxf(h, 0.0f);
            o[t][0] = fmaf(h, va.x, o[t][0]);
            o[t][1] = fmaf(h, va.y, o[t][1]);
            o[t][2] = fmaf(h, va.z, o[t][2]);
            o[t][3] = fmaf(h, va.w, o[t][3]);
            o[t][4] = fmaf(h, vb.x, o[t][4]);
            o[t][5] = fmaf(h, vb.y, o[t][5]);
            o[t][6] = fmaf(h, vb.z, o[t][6]);
            o[t][7] = fmaf(h, vb.w, o[t][7]);
        }
        wa = nwa; wb = nwb; va = nva; vb = nvb; bb = nbb;
    }

#pragma unroll
    for (int t = 0; t < TOKT; ++t) {
        int g = base + t * stride;
        outv[2 * g]     = make_float4(o[t][0], o[t][1], o[t][2], o[t][3]);
        outv[2 * g + 1] = make_float4(o[t][4], o[t][5], o[t][6], o[t][7]);
    }
}

extern "C" void kernel_launch(void* const* d_in, const int* in_sizes, int n_in,
                              void* d_out, int out_size, void* d_ws, size_t ws_size,
                              hipStream_t stream) {
    const float* x     = (const float*)d_in[0];
    const float* theta = (const float*)d_in[1];
    const float* w1    = (const float*)d_in[2];
    const float* b1    = (const float*)d_in[3];
    const float* w2    = (const float*)d_in[4];
    const float* b2    = (const float*)d_in[5];
    float* out = (float*)d_out;

    const int ntok = in_sizes[0] / 8;                   // 524288
    const int grid = ntok / (TPB * TOKT);               // 1024, exact fit

    ffq_kernel<<<grid, TPB, 0, stream>>>(
        (const float4*)x, theta, w1, b1, w2, b2, (float4*)out);
}

// Round 10
// 81.274 us; speedup vs baseline: 1.0671x; 1.0246x over previous
//
#include <hip/hip_runtime.h>

// FeedForwardQuantum: out = relu(cos(x+theta) @ W1 + b1) @ W2 + b2
// x: [B,S,E=8] fp32, W1: [8,32], W2: [32,8]. 524288 tokens = 32768 tiles of 16.
//
// R10 = R8/R9 with the C->B transform fixed: the lo/hi pack choice must be
// made by the TARGET lane's quad (after the pull), not the source lane's.
// R9's source-side select swapped B rows f[8,16) <-> [16,24) for target
// quads 1,2 -> absmax 0.71. Now: 8 ds_bpermute (both halves) + 4 selects.
//
// Design: weights live ONCE per wave in MFMA A-fragments (12 VGPRs) --
// eliminates the per-f-iter shared-pipe weight refetch that pinned
// R1/R4/R6/R7 at ~18us. Per 16-token tile: 2 MFMA (H^T = W1^T.Q^T + b1),
// relu, layout transform, 1 MFMA (O^T = W2^T.H^T + b2).
// Layouts (guide-verified): A[m=lane&15][k=quad*8+j],
// D[row=quad*4+reg][col=lane&15], B[k=quad*8+j][n=lane&15].

#define TPB 256

typedef _Float16 h8 __attribute__((ext_vector_type(8)));
typedef __fp16   fp16x2 __attribute__((ext_vector_type(2)));
typedef float    f4 __attribute__((ext_vector_type(4)));

union H2I { fp16x2 h; int i; };
union I4H8 { int i[4]; h8 h; };

__device__ __forceinline__ int pack_f16(float a, float b) {
    H2I u;
    u.h = __builtin_amdgcn_cvt_pkrtz(a, b);   // low=a, high=b
    return u.i;
}

__global__ __launch_bounds__(TPB) void ffq_kernel(
    const float4* __restrict__ xv,      // x as float4 pairs: token g -> xv[2g], xv[2g+1]
    const float*  __restrict__ theta,   // [8]
    const float*  __restrict__ w1,      // [8][32] row-major
    const float*  __restrict__ b1,      // [32]
    const float*  __restrict__ w2,      // [32][8] row-major
    const float*  __restrict__ b2,      // [8]
    float4*       __restrict__ outv,    // out as float4 pairs
    int ntile, int nwaves)
{
    const int tid  = threadIdx.x;
    const int lane = tid & 63;
    const int widx = tid >> 6;
    const int quad = lane >> 4;
    const int m16  = lane & 15;

    // ---- one-time setup: weight fragments in registers ----
    h8 a1lo, a1hi, a2;
#pragma unroll
    for (int j = 0; j < 8; ++j) { a1lo[j] = (_Float16)0; a1hi[j] = (_Float16)0; a2[j] = (_Float16)0; }

    if (quad == 0) {
        // A1[m=f][k=e]: real k only 0..7 (quad 0). f = m16 (lo) / m16+16 (hi).
#pragma unroll
        for (int j = 0; j < 8; ++j) {
            a1lo[j] = (_Float16)w1[j * 32 + m16];
            a1hi[j] = (_Float16)w1[j * 32 + 16 + m16];
        }
    }
    if (m16 < 8) {
        // A2[m=e][k=f]: e = m16 (real if <8), f = quad*8+j.
#pragma unroll
        for (int j = 0; j < 8; ++j)
            a2[j] = (_Float16)w2[(quad * 8 + j) * 8 + m16];
    }

    // Bias C-inits. D row m = quad*4 + reg.
    f4 c1lo0, c1hi0, c20;
#pragma unroll
    for (int r = 0; r < 4; ++r) {
        c1lo0[r] = b1[quad * 4 + r];
        c1hi0[r] = b1[16 + quad * 4 + r];
        c20[r]   = (quad < 2) ? b2[quad * 4 + r] : 0.0f;
    }

    float th[8];
#pragma unroll
    for (int e = 0; e < 8; ++e) th[e] = theta[e];

    // bpermute byte-addresses: src lane = qs*16 + t, qs = (2q + (p>>1)) & 3.
    const int addr0 = (((2 * quad) & 3) * 16 + m16) * 4;      // p = 0,1
    const int addr1 = (((2 * quad + 1) & 3) * 16 + m16) * 4;  // p = 2,3

    const int wid = blockIdx.x * (TPB / 64) + widx;

    // distance-1 x prefetch
    float4 curA = make_float4(0.f, 0.f, 0.f, 0.f);
    float4 curC = curA;
    if (wid < ntile && lane < 16) {
        const int tok = wid * 16 + lane;
        curA = xv[2 * tok];
        curC = xv[2 * tok + 1];
    }

    for (int tile = wid; tile < ntile; tile += nwaves) {
        float4 nA = curA, nC = curC;
        const int nxt = tile + nwaves;
        if (nxt < ntile && lane < 16) {
            const int tok = nxt * 16 + lane;
            nA = xv[2 * tok];
            nC = xv[2 * tok + 1];
        }

        // ---- B1 = Q^T fragment: lanes 0-15 hold token m16's q[0..7]; k>=8 zero ----
        h8 bq;
#pragma unroll
        for (int j = 0; j < 8; ++j) bq[j] = (_Float16)0;
        if (lane < 16) {
            bq[0] = (_Float16)__cosf(curA.x + th[0]);
            bq[1] = (_Float16)__cosf(curA.y + th[1]);
            bq[2] = (_Float16)__cosf(curA.z + th[2]);
            bq[3] = (_Float16)__cosf(curA.w + th[3]);
            bq[4] = (_Float16)__cosf(curC.x + th[4]);
            bq[5] = (_Float16)__cosf(curC.y + th[5]);
            bq[6] = (_Float16)__cosf(curC.z + th[6]);
            bq[7] = (_Float16)__cosf(curC.w + th[7]);
        }

        // ---- H^T = W1^T . Q^T + b1 ----
        f4 c1lo = __builtin_amdgcn_mfma_f32_16x16x32_f16(a1lo, bq, c1lo0, 0, 0, 0);
        f4 c1hi = __builtin_amdgcn_mfma_f32_16x16x32_f16(a1hi, bq, c1hi0, 0, 0, 0);

        // relu
#pragma unroll
        for (int r = 0; r < 4; ++r) {
            c1lo[r] = fmaxf(c1lo[r], 0.0f);
            c1hi[r] = fmaxf(c1hi[r], 0.0f);
        }

        // ---- C-layout -> B-operand layout ----
        // Source lane (qs, t): lo packs = (H[t][4qs+0],[+1]) / ([+2],[+3]);
        //                      hi packs = f+16 versions.
        // Target lane (q, t), int p: needs pair f = 8q+2p, 8q+2p+1:
        //   half by TARGET q (lo if q<2), pack01 if p even else pack23,
        //   src lane = ((2q + (p>>1)) & 3)*16 + t.
        const int lo01 = pack_f16(c1lo[0], c1lo[1]);
        const int lo23 = pack_f16(c1lo[2], c1lo[3]);
        const int hi01 = pack_f16(c1hi[0], c1hi[1]);
        const int hi23 = pack_f16(c1hi[2], c1hi[3]);

        const int tL0 = __builtin_amdgcn_ds_bpermute(addr0, lo01);
        const int tL1 = __builtin_amdgcn_ds_bpermute(addr0, lo23);
        const int tL2 = __builtin_amdgcn_ds_bpermute(addr1, lo01);
        const int tL3 = __builtin_amdgcn_ds_bpermute(addr1, lo23);
        const int tH0 = __builtin_amdgcn_ds_bpermute(addr0, hi01);
        const int tH1 = __builtin_amdgcn_ds_bpermute(addr0, hi23);
        const int tH2 = __builtin_amdgcn_ds_bpermute(addr1, hi01);
        const int tH3 = __builtin_amdgcn_ds_bpermute(addr1, hi23);

        I4H8 bh;
        bh.i[0] = (quad < 2) ? tL0 : tH0;   // p=0: f = 8q+0,1
        bh.i[1] = (quad < 2) ? tL1 : tH1;   // p=1: f = 8q+2,3
        bh.i[2] = (quad < 2) ? tL2 : tH2;   // p=2: f = 8q+4,5
        bh.i[3] = (quad < 2) ? tL3 : tH3;   // p=3: f = 8q+6,7

        // ---- O^T = W2^T . H^T + b2 ----
        f4 o = __builtin_amdgcn_mfma_f32_16x16x32_f16(a2, bh.h, c20, 0, 0, 0);

        // D row m = quad*4+r = e. Lane (q<2, t) stores out[t][4q..4q+3].
        if (quad < 2) {
            const int tok = tile * 16 + m16;
            outv[2 * tok + quad] = make_float4(o[0], o[1], o[2], o[3]);
        }

        curA = nA; curC = nC;
    }
}

extern "C" void kernel_launch(void* const* d_in, const int* in_sizes, int n_in,
                              void* d_out, int out_size, void* d_ws, size_t ws_size,
                              hipStream_t stream) {
    const float* x     = (const float*)d_in[0];
    const float* theta = (const float*)d_in[1];
    const float* w1    = (const float*)d_in[2];
    const float* b1    = (const float*)d_in[3];
    const float* w2    = (const float*)d_in[4];
    const float* b2    = (const float*)d_in[5];
    float* out = (float*)d_out;

    const int ntok  = in_sizes[0] / 8;     // 524288
    const int ntile = ntok / 16;           // 32768 (exact)
    const int grid  = 1024;                // 4096 waves -> 8 tiles/wave
    const int nwaves = grid * (TPB / 64);

    ffq_kernel<<<grid, TPB, 0, stream>>>(
        (const float4*)x, theta, w1, b1, w2, b2, (float4*)out, ntile, nwaves);
}